// Round 14
// baseline (106.871 us; speedup 1.0000x reference)
//
#include <hip/hip_runtime.h>
#include <stdint.h>

#define N_ROWS   16384
#define IN_DIM   512
#define CB_DIM   16
#define CB_VOCAB 8192

// ---- front geometry
#define PROJ_BLOCKS 1024                         // 1 row-tile each, 4-wave split-K
#define PREP_BLOCKS 128                          // 4 code-tiles each + part/cnt zero

// ---- scan geometry (R11's measured ~34us shape)
#define N_CT   (CB_VOCAB / 16)                   // 512 code-tiles
#define CODEPARTS 8
#define CT_PER_PART (N_CT / CODEPARTS)           // 64
#define N_ROWGRP 64                              // 256 rows per rowgrp

// ---- workspace layout (bytes), ~3.2 MB
#define WS_OFF_AFA  0                            // A-frag [A1|A2]: 1 MB
#define WS_OFF_AFB  (1u << 20)                   // A-frag [A1|A3]: 1 MB
#define WS_OFF_BHH  (2u << 20)                   // B-frag [B1;B2]: 512 KB
#define WS_OFF_B31  ((2u << 20) + (512u << 10))  // B-frag [B3;B1]: 512 KB
#define WS_OFF_PART (3u << 20)                   // u64[16384]: 128 KB
#define WS_OFF_CNT  ((3u << 20) + (128u << 10))  // u32[64]

#define XPAD 520                                 // LDS row stride (floats), 16B-aligned

typedef __attribute__((ext_vector_type(8))) short bf16x8;
typedef __attribute__((ext_vector_type(4))) float f32x4;

// monotone float -> uint32 key (order-preserving)
__device__ __forceinline__ unsigned fkey(float f) {
    unsigned u = __float_as_uint(f);
    return (u & 0x80000000u) ? ~u : (u | 0x80000000u);
}

// fp32 -> bf16 bits, round-to-nearest-even
__device__ __forceinline__ unsigned short f2bf(float f) {
    unsigned u = __float_as_uint(f);
    return (unsigned short)((u + 0x7FFFu + ((u >> 16) & 1u)) >> 16);
}
__device__ __forceinline__ float bf2f(unsigned short h) {
    return __uint_as_float(((unsigned)h) << 16);
}

// ---------------- K1: MFMA projection (blocks 0..1023) + prep (1024..1151) --
// R13 front (resubmitted -- R13's bench died on container infra, kernel never
// measured): coalesced x via LDS staging. R12 post-mortem: front pinned at
// 27-31 us across 5 rewrites because the x read was ALWAYS strided -- lane
// (m,kq) reading 16 B at 2 KB row-stride = 16 disjoint 64-B segments per
// wave-load, half of every 128-B line wasted + DRAM row thrash from 1024
// interleaved scatter streams -> measured 32 MB / 28.5 us = 1.1 TB/s (same
// number R2 measured for the old front). Fix: a row-tile's x is 32 KB
// CONTIGUOUS; phase 0 loads it linearly (thread t reads float4 t+i*256;
// 1 KB/instruction, full lines, sequential DRAM) into a padded LDS tile
// [16][XPAD=520] (b128-aligned, ~4-way aliasing = cheap). One barrier; the
// MFMA loop then reads fragments from LDS. P-frag register path, truncate
// splits, MFMA chains, fold, epilogue byte-identical R12.
__global__ __launch_bounds__(256, 3)
void k_front(const float* __restrict__ x, const float* __restrict__ P,
             const float* __restrict__ CB,
             bf16x8* __restrict__ AfragA, bf16x8* __restrict__ AfragB,
             bf16x8* __restrict__ Bhh, bf16x8* __restrict__ B31,
             unsigned long long* __restrict__ part, unsigned* __restrict__ cnt) {
    __shared__ __align__(16) float xs[16 * XPAD];   // staged x-tile: 33.3 KB
    __shared__ __align__(16) float foldb[1024];     // split-K fold / transpose: 4 KB

    const int tid  = threadIdx.x;
    const int wave = tid >> 6;
    const int lane = tid & 63;

    if (blockIdx.x >= PROJ_BLOCKS) {
        // ---- prep path: zero part/cnt, build CB B-frags (unchanged) ----
        const int pb = blockIdx.x - PROJ_BLOCKS;
        if (tid < 128) part[pb * 128 + tid] = 0ull;
        if (pb == 0 && tid < 64) cnt[tid] = 0u;

        const int ct   = pb * 4 + wave;
        const int n    = lane & 15;
        const int quad = lane >> 4;
        const int kh   = (quad & 1) * 8;
        const int lvl  = quad >> 1;
        const int code = ct * 16 + n;

        const float4* b4 = (const float4*)(CB + (size_t)code * CB_DIM + kh);
        float4 a = b4[0], b = b4[1];
        float v[8] = {a.x, a.y, a.z, a.w, b.x, b.y, b.z, b.w};

        bf16x8 shh, s31;
#pragma unroll
        for (int j = 0; j < 8; ++j) {
            float f = v[j];
            unsigned short b1 = f2bf(f);  float r1 = f - bf2f(b1);
            unsigned short b2 = f2bf(r1); float r2 = r1 - bf2f(b2);
            unsigned short b3 = f2bf(r2);
            shh[j] = (short)(lvl ? b2 : b1);
            s31[j] = (short)(lvl ? b1 : b3);
        }
        Bhh[(size_t)ct * 64 + lane] = shh;
        B31[(size_t)ct * 64 + lane] = s31;
        return;
    }

    // ---- Phase 0: linear coalesced x stage (32 KB contiguous -> LDS) ----
    const int rt = blockIdx.x;
    const float4* xg = (const float4*)(x + (size_t)rt * 16 * IN_DIM);
#pragma unroll
    for (int i = 0; i < 8; ++i) {
        const int f4  = tid + i * 256;           // 0..2047
        float4 v = xg[f4];
        const int row = f4 >> 7;                 // /128 f4-per-row
        const int col = f4 & 127;
        *(float4*)&xs[row * XPAD + col * 4] = v;
    }
    __syncthreads();

    // ---- Phase B: split-K proj; wave w covers chunks 4w..4w+3 ----
    const int m  = lane & 15;
    const int kq = lane >> 4;
    const float* xrow = &xs[m * XPAD];

    // raw P loads for this lane's 4 chunks (upfront, L1/L2-hot; static idx)
    float praw[4][8];
#pragma unroll
    for (int i = 0; i < 4; ++i) {
        const float* pg =
            P + (size_t)((wave * 4 + i) * 32 + kq * 8) * CB_DIM + m;
#pragma unroll
        for (int j = 0; j < 8; ++j) praw[i][j] = pg[j * CB_DIM];
    }

    f32x4 acc1 = {0.f, 0.f, 0.f, 0.f};
    f32x4 acc2 = {0.f, 0.f, 0.f, 0.f};

#pragma unroll
    for (int i = 0; i < 4; ++i) {
        bf16x8 p1, p2, p3;
#pragma unroll
        for (int j = 0; j < 8; ++j) {
            // truncate split: exact f = p1 + p2 + p3
            float f = praw[i][j];
            unsigned u  = __float_as_uint(f);
            unsigned h1 = u & 0xFFFF0000u;
            float r1 = f - __uint_as_float(h1);
            unsigned u2 = __float_as_uint(r1);
            float r2 = r1 - __uint_as_float(u2 & 0xFFFF0000u);
            p1[j] = (short)(h1 >> 16);
            p2[j] = (short)(u2 >> 16);
            p3[j] = (short)(__float_as_uint(r2) >> 16);
        }

        const int c = wave * 4 + i;
        float4 xa = *(const float4*)&xrow[c * 32 + kq * 8];
        float4 xb = *(const float4*)&xrow[c * 32 + kq * 8 + 4];
        float xs8[8] = {xa.x, xa.y, xa.z, xa.w, xb.x, xb.y, xb.z, xb.w};
        bf16x8 a1, a2, a3;
#pragma unroll
        for (int j = 0; j < 8; ++j) {
            // truncate split: exact f = a1 + a2 + a3
            float f = xs8[j];
            unsigned u  = __float_as_uint(f);
            unsigned h1 = u & 0xFFFF0000u;
            float r1 = f - __uint_as_float(h1);
            unsigned u2 = __float_as_uint(r1);
            float r2 = r1 - __uint_as_float(u2 & 0xFFFF0000u);
            a1[j] = (short)(h1 >> 16);
            a2[j] = (short)(u2 >> 16);
            a3[j] = (short)(__float_as_uint(r2) >> 16);
        }

        // terms i+j<=4: (1,1)(2,1)(2,2) chain1; (1,2)(1,3)(3,1) chain2
        acc1 = __builtin_amdgcn_mfma_f32_16x16x32_bf16(a1, p1, acc1, 0, 0, 0);
        acc2 = __builtin_amdgcn_mfma_f32_16x16x32_bf16(a1, p2, acc2, 0, 0, 0);
        acc1 = __builtin_amdgcn_mfma_f32_16x16x32_bf16(a2, p1, acc1, 0, 0, 0);
        acc2 = __builtin_amdgcn_mfma_f32_16x16x32_bf16(a1, p3, acc2, 0, 0, 0);
        acc1 = __builtin_amdgcn_mfma_f32_16x16x32_bf16(a2, p2, acc1, 0, 0, 0);
        acc2 = __builtin_amdgcn_mfma_f32_16x16x32_bf16(a3, p1, acc2, 0, 0, 0);
    }

    *(f32x4*)&foldb[(wave * 64 + lane) * 4] = acc1 + acc2;
    __syncthreads();

    // ---- Phase C (wave 0): fold partials, transpose, split, store ----
    if (wave == 0) {
        f32x4 s0 = *(const f32x4*)&foldb[(0 * 64 + lane) * 4];
        f32x4 s1 = *(const f32x4*)&foldb[(1 * 64 + lane) * 4];
        f32x4 s2 = *(const f32x4*)&foldb[(2 * 64 + lane) * 4];
        f32x4 s3 = *(const f32x4*)&foldb[(3 * 64 + lane) * 4];
        f32x4 sum = ((s0 + s1) + s2) + s3;

        // reads must retire before we overwrite foldb (rule 18 fence)
        asm volatile("s_waitcnt lgkmcnt(0)" ::: "memory");
        __builtin_amdgcn_sched_barrier(0);

        // C layout: lane holds xp[row=(kq*4+r)][col=m] -> transpose [16][20]
#pragma unroll
        for (int r = 0; r < 4; ++r)
            foldb[(kq * 4 + r) * 20 + m] = sum[r];

        asm volatile("s_waitcnt lgkmcnt(0)" ::: "memory");
        __builtin_amdgcn_sched_barrier(0);

        const int kh  = (kq & 1) * 8;
        const int lvl = kq >> 1;
        bf16x8 sa, sb;
#pragma unroll
        for (int j = 0; j < 8; ++j) {
            float f = foldb[m * 20 + kh + j];
            unsigned short b1 = f2bf(f);  float r1 = f - bf2f(b1);
            unsigned short b2 = f2bf(r1); float r2 = r1 - bf2f(b2);
            unsigned short b3 = f2bf(r2);
            sa[j] = (short)(lvl ? b2 : b1);
            sb[j] = (short)(lvl ? b3 : b1);
        }
        AfragA[(size_t)rt * 64 + lane] = sa;
        AfragB[(size_t)rt * 64 + lane] = sb;
    }
}

// ---------------- K2: MFMA sim + argmax + last-block finalize ---------------
// BYTE-IDENTICAL to R11/R12 (measured ~34 us): grid 512 = 64 rowgrps x 8
// codeparts, 64 c-iters/block, depth-1 named prefetch, LDS tail, setprio.
__global__ __launch_bounds__(256, 4)
void k_scan(const bf16x8* __restrict__ AfragA, const bf16x8* __restrict__ AfragB,
            const bf16x8* __restrict__ Bhh, const bf16x8* __restrict__ B31,
            unsigned long long* __restrict__ part, unsigned* __restrict__ cnt,
            int* __restrict__ out) {
    __shared__ unsigned long long Lcand[16][257];  // [cand n][row_loc], padded
    __shared__ int s_done;
    const int codepart = blockIdx.x & (CODEPARTS - 1);
    const int rowgrp   = blockIdx.x >> 3;
    const int wave     = threadIdx.x >> 6;
    const int lane     = threadIdx.x & 63;
    const int n        = lane & 15;
    const int quad     = lane >> 4;
    const int rt_base  = rowgrp * 16 + wave * 4;

    bf16x8 Aa[4], Ab[4];
#pragma unroll
    for (int t = 0; t < 4; ++t) {
        Aa[t] = AfragA[(size_t)(rt_base + t) * 64 + lane];
        Ab[t] = AfragB[(size_t)(rt_base + t) * 64 + lane];
    }

    float bestv[4][4];
    int   bestc[4][4];
#pragma unroll
    for (int t = 0; t < 4; ++t)
#pragma unroll
        for (int r = 0; r < 4; ++r) { bestv[t][r] = -INFINITY; bestc[t][r] = 0; }

    const int ct0 = codepart * CT_PER_PART;
    size_t ib = (size_t)ct0 * 64;
    bf16x8 nb1  = Bhh[ib + lane];
    bf16x8 nb1s = Bhh[ib + (lane ^ 32)];
    bf16x8 nb3  = B31[ib + lane];

    for (int c = 0; c < CT_PER_PART; ++c) {
        bf16x8 b1 = nb1, b1s = nb1s, b3 = nb3;
        if (c + 1 < CT_PER_PART) {
            size_t ibn = (size_t)(ct0 + c + 1) * 64;
            nb1  = Bhh[ibn + lane];
            nb1s = Bhh[ibn + (lane ^ 32)];
            nb3  = B31[ibn + lane];
        }
        __builtin_amdgcn_s_setprio(1);
#pragma unroll
        for (int t = 0; t < 4; ++t) {
            f32x4 s = __builtin_amdgcn_mfma_f32_16x16x32_bf16(
                          Aa[t], b1, (f32x4){0.f, 0.f, 0.f, 0.f}, 0, 0, 0);
            s = __builtin_amdgcn_mfma_f32_16x16x32_bf16(Aa[t], b1s, s, 0, 0, 0);
            s = __builtin_amdgcn_mfma_f32_16x16x32_bf16(Ab[t], b3,  s, 0, 0, 0);
#pragma unroll
            for (int r = 0; r < 4; ++r) {
                if (s[r] > bestv[t][r]) { bestv[t][r] = s[r]; bestc[t][r] = c; }
            }
        }
        __builtin_amdgcn_s_setprio(0);
    }

    // ---- LDS tail: every lane deposits its candidate; no cross-lane ops ----
#pragma unroll
    for (int t = 0; t < 4; ++t) {
#pragma unroll
        for (int r = 0; r < 4; ++r) {
            unsigned code = (unsigned)(codepart * (CT_PER_PART * 16) +
                                       bestc[t][r] * 16 + n);
            unsigned long long packed =
                ((unsigned long long)fkey(bestv[t][r]) << 32) |
                (unsigned long long)(0xFFFFFFFFu - code);
            const int row_loc = (wave * 4 + t) * 16 + quad * 4 + r;
            Lcand[n][row_loc] = packed;
        }
    }
    __syncthreads();

    // thread i owns block-row i: serial max over its 16 candidates, 1 atomic
    {
        const int i = threadIdx.x;                // 0..255 == row_loc
        unsigned long long best = Lcand[0][i];
#pragma unroll
        for (int j = 1; j < 16; ++j) {
            unsigned long long v = Lcand[j][i];
            best = (v > best) ? v : best;
        }
        atomicMax(&part[rowgrp * 256 + i], best);
    }

    // __syncthreads drains vmcnt -> all this block's atomics are complete
    __syncthreads();
    if (threadIdx.x == 0)
        s_done = (atomicAdd(&cnt[rowgrp], 1u) == (unsigned)(CODEPARTS - 1));
    __syncthreads();

    if (s_done) {
        int row = rowgrp * 256 + threadIdx.x;
        unsigned long long v = atomicAdd(&part[row], 0ull);   // coherent read
        out[row] = (int)(0xFFFFFFFFu - (unsigned)(v & 0xFFFFFFFFull));
    }
}

extern "C" void kernel_launch(void* const* d_in, const int* in_sizes, int n_in,
                              void* d_out, int out_size, void* d_ws, size_t ws_size,
                              hipStream_t stream) {
    const float* x  = (const float*)d_in[0];   // [16384, 512]
    const float* P  = (const float*)d_in[1];   // [512, 16]
    const float* CB = (const float*)d_in[2];   // [8192, 16]
    int* out = (int*)d_out;                    // [16384] int32

    char* ws = (char*)d_ws;
    bf16x8* AfragA = (bf16x8*)(ws + WS_OFF_AFA);
    bf16x8* AfragB = (bf16x8*)(ws + WS_OFF_AFB);
    bf16x8* Bhh    = (bf16x8*)(ws + WS_OFF_BHH);
    bf16x8* B31    = (bf16x8*)(ws + WS_OFF_B31);
    unsigned long long* part = (unsigned long long*)(ws + WS_OFF_PART);
    unsigned* cnt  = (unsigned*)(ws + WS_OFF_CNT);

    k_front<<<PROJ_BLOCKS + PREP_BLOCKS, 256, 0, stream>>>(
        x, P, CB, AfragA, AfragB, Bhh, B31, part, cnt);            // 1152 blocks
    k_scan<<<N_ROWGRP * CODEPARTS, 256, 0, stream>>>(
        AfragA, AfragB, Bhh, B31, part, cnt, out);                 // 512 blocks
}

// Round 15
// 106.846 us; speedup vs baseline: 1.0002x; 1.0002x over previous
//
#include <hip/hip_runtime.h>
#include <stdint.h>

#define N_ROWS   16384
#define IN_DIM   512
#define CB_DIM   16
#define CB_VOCAB 8192

// ---- front geometry
#define PROJ_BLOCKS 1024                         // 1 row-tile each, 4-wave split-K
#define PREP_BLOCKS 128                          // 4 code-tiles each + part/cnt zero

// ---- scan geometry: R15 = 64 iters AND 4 blocks/CU.
// Amortization series (iters/blk -> us): 16->50, 32->38.8, 64->34.2 -- kept
// improving even as blocks/CU fell 8->4->2 (confounded). De-confound: 128
// rowgrps x 8 rt (2 rt/wave) x 8 codeparts = grid 1024 = 4 blocks/CU,
// keeping the 64-iter fat loop AND doubling resident waves (8->16/CU).
#define N_CT   (CB_VOCAB / 16)                   // 512 code-tiles
#define CODEPARTS 8
#define CT_PER_PART (N_CT / CODEPARTS)           // 64
#define N_ROWGRP 128                             // 128 rows per rowgrp

// ---- workspace layout (bytes), ~3.2 MB
#define WS_OFF_AFA  0                            // A-frag [A1|A2]: 1 MB
#define WS_OFF_AFB  (1u << 20)                   // A-frag [A1|A3]: 1 MB
#define WS_OFF_BHH  (2u << 20)                   // B-frag [B1;B2]: 512 KB
#define WS_OFF_B31  ((2u << 20) + (512u << 10))  // B-frag [B3;B1]: 512 KB
#define WS_OFF_PART (3u << 20)                   // u64[16384]: 128 KB
#define WS_OFF_CNT  ((3u << 20) + (128u << 10))  // u32[128]

#define XPAD 520                                 // LDS row stride (floats), 16B-aligned

typedef __attribute__((ext_vector_type(8))) short bf16x8;
typedef __attribute__((ext_vector_type(4))) float f32x4;

// monotone float -> uint32 key (order-preserving)
__device__ __forceinline__ unsigned fkey(float f) {
    unsigned u = __float_as_uint(f);
    return (u & 0x80000000u) ? ~u : (u | 0x80000000u);
}

// fp32 -> bf16 bits, round-to-nearest-even
__device__ __forceinline__ unsigned short f2bf(float f) {
    unsigned u = __float_as_uint(f);
    return (unsigned short)((u + 0x7FFFu + ((u >> 16) & 1u)) >> 16);
}
__device__ __forceinline__ float bf2f(unsigned short h) {
    return __uint_as_float(((unsigned)h) << 16);
}

// ---------------- K1: MFMA projection (blocks 0..1023) + prep (1024..1151) --
// BYTE-IDENTICAL to R14 except cnt zeroing covers 128 rowgrps. R14's null
// (coalesced x = no change) closed the front investigation: its ~28 us is
// invariant to access pattern, occupancy, LDS, and VALU count -- i.e. not a
// property of the kernel. Best model: the 268-MB poison-fill's dirty-L3
// drain bleeds into this dispatch's head (~15-20 us) + ~10 us true work.
// Harness physics; front is frozen.
__global__ __launch_bounds__(256, 3)
void k_front(const float* __restrict__ x, const float* __restrict__ P,
             const float* __restrict__ CB,
             bf16x8* __restrict__ AfragA, bf16x8* __restrict__ AfragB,
             bf16x8* __restrict__ Bhh, bf16x8* __restrict__ B31,
             unsigned long long* __restrict__ part, unsigned* __restrict__ cnt) {
    __shared__ __align__(16) float xs[16 * XPAD];   // staged x-tile: 33.3 KB
    __shared__ __align__(16) float foldb[1024];     // split-K fold / transpose: 4 KB

    const int tid  = threadIdx.x;
    const int wave = tid >> 6;
    const int lane = tid & 63;

    if (blockIdx.x >= PROJ_BLOCKS) {
        // ---- prep path: zero part/cnt, build CB B-frags ----
        const int pb = blockIdx.x - PROJ_BLOCKS;
        if (tid < 128) part[pb * 128 + tid] = 0ull;
        if (pb == 0 && tid < 128) cnt[tid] = 0u;

        const int ct   = pb * 4 + wave;
        const int n    = lane & 15;
        const int quad = lane >> 4;
        const int kh   = (quad & 1) * 8;
        const int lvl  = quad >> 1;
        const int code = ct * 16 + n;

        const float4* b4 = (const float4*)(CB + (size_t)code * CB_DIM + kh);
        float4 a = b4[0], b = b4[1];
        float v[8] = {a.x, a.y, a.z, a.w, b.x, b.y, b.z, b.w};

        bf16x8 shh, s31;
#pragma unroll
        for (int j = 0; j < 8; ++j) {
            float f = v[j];
            unsigned short b1 = f2bf(f);  float r1 = f - bf2f(b1);
            unsigned short b2 = f2bf(r1); float r2 = r1 - bf2f(b2);
            unsigned short b3 = f2bf(r2);
            shh[j] = (short)(lvl ? b2 : b1);
            s31[j] = (short)(lvl ? b1 : b3);
        }
        Bhh[(size_t)ct * 64 + lane] = shh;
        B31[(size_t)ct * 64 + lane] = s31;
        return;
    }

    // ---- Phase 0: linear coalesced x stage (32 KB contiguous -> LDS) ----
    const int rt = blockIdx.x;
    const float4* xg = (const float4*)(x + (size_t)rt * 16 * IN_DIM);
#pragma unroll
    for (int i = 0; i < 8; ++i) {
        const int f4  = tid + i * 256;           // 0..2047
        float4 v = xg[f4];
        const int row = f4 >> 7;                 // /128 f4-per-row
        const int col = f4 & 127;
        *(float4*)&xs[row * XPAD + col * 4] = v;
    }
    __syncthreads();

    // ---- Phase B: split-K proj; wave w covers chunks 4w..4w+3 ----
    const int m  = lane & 15;
    const int kq = lane >> 4;
    const float* xrow = &xs[m * XPAD];

    // raw P loads for this lane's 4 chunks (upfront, L1/L2-hot; static idx)
    float praw[4][8];
#pragma unroll
    for (int i = 0; i < 4; ++i) {
        const float* pg =
            P + (size_t)((wave * 4 + i) * 32 + kq * 8) * CB_DIM + m;
#pragma unroll
        for (int j = 0; j < 8; ++j) praw[i][j] = pg[j * CB_DIM];
    }

    f32x4 acc1 = {0.f, 0.f, 0.f, 0.f};
    f32x4 acc2 = {0.f, 0.f, 0.f, 0.f};

#pragma unroll
    for (int i = 0; i < 4; ++i) {
        bf16x8 p1, p2, p3;
#pragma unroll
        for (int j = 0; j < 8; ++j) {
            // truncate split: exact f = p1 + p2 + p3
            float f = praw[i][j];
            unsigned u  = __float_as_uint(f);
            unsigned h1 = u & 0xFFFF0000u;
            float r1 = f - __uint_as_float(h1);
            unsigned u2 = __float_as_uint(r1);
            float r2 = r1 - __uint_as_float(u2 & 0xFFFF0000u);
            p1[j] = (short)(h1 >> 16);
            p2[j] = (short)(u2 >> 16);
            p3[j] = (short)(__float_as_uint(r2) >> 16);
        }

        const int c = wave * 4 + i;
        float4 xa = *(const float4*)&xrow[c * 32 + kq * 8];
        float4 xb = *(const float4*)&xrow[c * 32 + kq * 8 + 4];
        float xs8[8] = {xa.x, xa.y, xa.z, xa.w, xb.x, xb.y, xb.z, xb.w};
        bf16x8 a1, a2, a3;
#pragma unroll
        for (int j = 0; j < 8; ++j) {
            // truncate split: exact f = a1 + a2 + a3
            float f = xs8[j];
            unsigned u  = __float_as_uint(f);
            unsigned h1 = u & 0xFFFF0000u;
            float r1 = f - __uint_as_float(h1);
            unsigned u2 = __float_as_uint(r1);
            float r2 = r1 - __uint_as_float(u2 & 0xFFFF0000u);
            a1[j] = (short)(h1 >> 16);
            a2[j] = (short)(u2 >> 16);
            a3[j] = (short)(__float_as_uint(r2) >> 16);
        }

        // terms i+j<=4: (1,1)(2,1)(2,2) chain1; (1,2)(1,3)(3,1) chain2
        acc1 = __builtin_amdgcn_mfma_f32_16x16x32_bf16(a1, p1, acc1, 0, 0, 0);
        acc2 = __builtin_amdgcn_mfma_f32_16x16x32_bf16(a1, p2, acc2, 0, 0, 0);
        acc1 = __builtin_amdgcn_mfma_f32_16x16x32_bf16(a2, p1, acc1, 0, 0, 0);
        acc2 = __builtin_amdgcn_mfma_f32_16x16x32_bf16(a1, p3, acc2, 0, 0, 0);
        acc1 = __builtin_amdgcn_mfma_f32_16x16x32_bf16(a2, p2, acc1, 0, 0, 0);
        acc2 = __builtin_amdgcn_mfma_f32_16x16x32_bf16(a3, p1, acc2, 0, 0, 0);
    }

    *(f32x4*)&foldb[(wave * 64 + lane) * 4] = acc1 + acc2;
    __syncthreads();

    // ---- Phase C (wave 0): fold partials, transpose, split, store ----
    if (wave == 0) {
        f32x4 s0 = *(const f32x4*)&foldb[(0 * 64 + lane) * 4];
        f32x4 s1 = *(const f32x4*)&foldb[(1 * 64 + lane) * 4];
        f32x4 s2 = *(const f32x4*)&foldb[(2 * 64 + lane) * 4];
        f32x4 s3 = *(const f32x4*)&foldb[(3 * 64 + lane) * 4];
        f32x4 sum = ((s0 + s1) + s2) + s3;

        // reads must retire before we overwrite foldb (rule 18 fence)
        asm volatile("s_waitcnt lgkmcnt(0)" ::: "memory");
        __builtin_amdgcn_sched_barrier(0);

        // C layout: lane holds xp[row=(kq*4+r)][col=m] -> transpose [16][20]
#pragma unroll
        for (int r = 0; r < 4; ++r)
            foldb[(kq * 4 + r) * 20 + m] = sum[r];

        asm volatile("s_waitcnt lgkmcnt(0)" ::: "memory");
        __builtin_amdgcn_sched_barrier(0);

        const int kh  = (kq & 1) * 8;
        const int lvl = kq >> 1;
        bf16x8 sa, sb;
#pragma unroll
        for (int j = 0; j < 8; ++j) {
            float f = foldb[m * 20 + kh + j];
            unsigned short b1 = f2bf(f);  float r1 = f - bf2f(b1);
            unsigned short b2 = f2bf(r1); float r2 = r1 - bf2f(b2);
            unsigned short b3 = f2bf(r2);
            sa[j] = (short)(lvl ? b2 : b1);
            sb[j] = (short)(lvl ? b3 : b1);
        }
        AfragA[(size_t)rt * 64 + lane] = sa;
        AfragB[(size_t)rt * 64 + lane] = sb;
    }
}

// ---------------- K2: MFMA sim + argmax + last-block finalize ---------------
// R15: grid 1024 = 128 rowgrps x 8 codeparts; wave = 2 row-tiles x 64
// code-tiles. Keeps R11's 64-iter amortization, restores 4 blocks/CU = 16
// waves/CU (2x the latency cover). VGPR drops ~60 (Aa/Ab/best halve) -- no
// spill risk at (256,4). Depth-1 named prefetch, LDS tail, setprio retained.
__global__ __launch_bounds__(256, 4)
void k_scan(const bf16x8* __restrict__ AfragA, const bf16x8* __restrict__ AfragB,
            const bf16x8* __restrict__ Bhh, const bf16x8* __restrict__ B31,
            unsigned long long* __restrict__ part, unsigned* __restrict__ cnt,
            int* __restrict__ out) {
    __shared__ unsigned long long Lcand[16][132];  // [cand n][row_loc], padded
    __shared__ int s_done;
    const int codepart = blockIdx.x & (CODEPARTS - 1);
    const int rowgrp   = blockIdx.x >> 3;
    const int wave     = threadIdx.x >> 6;
    const int lane     = threadIdx.x & 63;
    const int n        = lane & 15;
    const int quad     = lane >> 4;
    const int rt_base  = rowgrp * 8 + wave * 2;

    bf16x8 Aa[2], Ab[2];
#pragma unroll
    for (int t = 0; t < 2; ++t) {
        Aa[t] = AfragA[(size_t)(rt_base + t) * 64 + lane];
        Ab[t] = AfragB[(size_t)(rt_base + t) * 64 + lane];
    }

    float bestv[2][4];
    int   bestc[2][4];
#pragma unroll
    for (int t = 0; t < 2; ++t)
#pragma unroll
        for (int r = 0; r < 4; ++r) { bestv[t][r] = -INFINITY; bestc[t][r] = 0; }

    const int ct0 = codepart * CT_PER_PART;
    size_t ib = (size_t)ct0 * 64;
    bf16x8 nb1  = Bhh[ib + lane];
    bf16x8 nb1s = Bhh[ib + (lane ^ 32)];
    bf16x8 nb3  = B31[ib + lane];

    for (int c = 0; c < CT_PER_PART; ++c) {
        bf16x8 b1 = nb1, b1s = nb1s, b3 = nb3;
        if (c + 1 < CT_PER_PART) {
            size_t ibn = (size_t)(ct0 + c + 1) * 64;
            nb1  = Bhh[ibn + lane];
            nb1s = Bhh[ibn + (lane ^ 32)];
            nb3  = B31[ibn + lane];
        }
        __builtin_amdgcn_s_setprio(1);
#pragma unroll
        for (int t = 0; t < 2; ++t) {
            f32x4 s = __builtin_amdgcn_mfma_f32_16x16x32_bf16(
                          Aa[t], b1, (f32x4){0.f, 0.f, 0.f, 0.f}, 0, 0, 0);
            s = __builtin_amdgcn_mfma_f32_16x16x32_bf16(Aa[t], b1s, s, 0, 0, 0);
            s = __builtin_amdgcn_mfma_f32_16x16x32_bf16(Ab[t], b3,  s, 0, 0, 0);
#pragma unroll
            for (int r = 0; r < 4; ++r) {
                if (s[r] > bestv[t][r]) { bestv[t][r] = s[r]; bestc[t][r] = c; }
            }
        }
        __builtin_amdgcn_s_setprio(0);
    }

    // ---- LDS tail: every lane deposits its candidate; no cross-lane ops ----
#pragma unroll
    for (int t = 0; t < 2; ++t) {
#pragma unroll
        for (int r = 0; r < 4; ++r) {
            unsigned code = (unsigned)(codepart * (CT_PER_PART * 16) +
                                       bestc[t][r] * 16 + n);
            unsigned long long packed =
                ((unsigned long long)fkey(bestv[t][r]) << 32) |
                (unsigned long long)(0xFFFFFFFFu - code);
            const int row_loc = (wave * 2 + t) * 16 + quad * 4 + r;
            Lcand[n][row_loc] = packed;
        }
    }
    __syncthreads();

    // threads 0..127 own block-rows: serial max over 16 candidates, 1 atomic
    if (threadIdx.x < 128) {
        const int i = threadIdx.x;                // row_loc
        unsigned long long best = Lcand[0][i];
#pragma unroll
        for (int j = 1; j < 16; ++j) {
            unsigned long long v = Lcand[j][i];
            best = (v > best) ? v : best;
        }
        atomicMax(&part[rowgrp * 128 + i], best);
    }

    // __syncthreads drains vmcnt -> all this block's atomics are complete
    __syncthreads();
    if (threadIdx.x == 0)
        s_done = (atomicAdd(&cnt[rowgrp], 1u) == (unsigned)(CODEPARTS - 1));
    __syncthreads();

    if (s_done && threadIdx.x < 128) {
        int row = rowgrp * 128 + threadIdx.x;
        unsigned long long v = atomicAdd(&part[row], 0ull);   // coherent read
        out[row] = (int)(0xFFFFFFFFu - (unsigned)(v & 0xFFFFFFFFull));
    }
}

extern "C" void kernel_launch(void* const* d_in, const int* in_sizes, int n_in,
                              void* d_out, int out_size, void* d_ws, size_t ws_size,
                              hipStream_t stream) {
    const float* x  = (const float*)d_in[0];   // [16384, 512]
    const float* P  = (const float*)d_in[1];   // [512, 16]
    const float* CB = (const float*)d_in[2];   // [8192, 16]
    int* out = (int*)d_out;                    // [16384] int32

    char* ws = (char*)d_ws;
    bf16x8* AfragA = (bf16x8*)(ws + WS_OFF_AFA);
    bf16x8* AfragB = (bf16x8*)(ws + WS_OFF_AFB);
    bf16x8* Bhh    = (bf16x8*)(ws + WS_OFF_BHH);
    bf16x8* B31    = (bf16x8*)(ws + WS_OFF_B31);
    unsigned long long* part = (unsigned long long*)(ws + WS_OFF_PART);
    unsigned* cnt  = (unsigned*)(ws + WS_OFF_CNT);

    k_front<<<PROJ_BLOCKS + PREP_BLOCKS, 256, 0, stream>>>(
        x, P, CB, AfragA, AfragB, Bhh, B31, part, cnt);            // 1152 blocks
    k_scan<<<N_ROWGRP * CODEPARTS, 256, 0, stream>>>(
        AfragA, AfragB, Bhh, B31, part, cnt, out);                 // 1024 blocks
}